// Round 3
// baseline (250.243 us; speedup 1.0000x reference)
//
#include <hip/hip_runtime.h>
#include <math.h>

#define BATCH 2048
#define TLEN  1440
#define T7    (TLEN * 7)      // 10080 dwords per batch row
#define CL0   48              // chunk 0 length (covers ENC_LEN=48 gt region)
#define CL2   16              // length of chunks 1..87
#define NCH   88              // total chunks per batch (1 + 87)
#define TREST (TLEN - CL0)    // 1392

// ---- workspace layout (float offsets) ----
#define E_OFF    0                               // [NCH][BATCH][8] chunk end-states
#define XC_OFF   (E_OFF + NCH * BATCH * 8)       // [BATCH][NCH][8] combined entry states
#define A16_OFF  (XC_OFF + BATCH * NCH * 8)      // 36 floats (pad 64)
#define V_OFF    (A16_OFF + 64)                  // [16][8]: V[kk][j] = row0(A^(kk+1))[j]
#define PRM_OFF  (V_OFF + 128)
#define WS_FLOATS (PRM_OFF + 32)

__device__ __forceinline__ float sp_precise(float x) { return log1pf(expf(x)); }

struct Prm {
  float P[5], M[5], Q[5], K[5];
  float AZ, dtczw, dtcz, cInt, cHv, cDir;
};
__device__ __forceinline__ Prm make_prm(const float* rcR, const float* rcC,
                                        const float* winR, const float* hvg,
                                        const float* ing, const float* dg,
                                        const float* aw, const float* ar,
                                        const float* zc) {
  Prm p;
  float r[5], cc[5], rsum = 0.f;
  #pragma unroll
  for (int j = 0; j < 5; ++j) {
    r[j] = sp_precise(rcR[j]) * 0.1f;
    cc[j] = sp_precise(rcC[j]) * 1e-5f;
    rsum += r[j];
  }
  float w  = (sp_precise(winR[0]) + sp_precise(winR[1])) * 0.5f;
  float cz = sp_precise(zc[0]) * 1e-5f;
  float aW = sp_precise(aw[0]) * 0.5f, aR = sp_precise(ar[0]) * 0.5f;
  float dtcz = 900.f * cz;
  #pragma unroll
  for (int j = 0; j < 5; ++j) {
    p.P[j] = 900.f * r[j] * cc[j];
    p.M[j] = 1.f - 2.f * p.P[j];
    p.Q[j] = 900.f * cc[j] * ((j < 4) ? aW : aR);
    p.K[j] = dtcz * r[j];
  }
  p.AZ = 1.f - dtcz * (w + rsum);
  p.dtczw = dtcz * w;
  p.dtcz = dtcz;
  p.cInt = sp_precise(ing[0]) * 0.1f;
  p.cHv  = sp_precise(hvg[0]) * 0.1f;
  p.cDir = sp_precise(dg[0])  * 0.5f;
  return p;
}

// ============ K0: derived params, A^16, V rows ============
__global__ void k0_params(const float* __restrict__ rcR, const float* __restrict__ rcC,
                          const float* __restrict__ winR, const float* __restrict__ hvg,
                          const float* __restrict__ ing, const float* __restrict__ dg,
                          const float* __restrict__ aw, const float* __restrict__ ar,
                          const float* __restrict__ zc, float* __restrict__ ws) {
  __shared__ float A0s[36], Ma[36], Mb[36], vrow[2][8];
  int ln = threadIdx.x;
  if (ln == 0) {
    Prm p = make_prm(rcR, rcC, winR, hvg, ing, dg, aw, ar, zc);
    float* prm = ws + PRM_OFF;
    for (int j = 0; j < 5; ++j) {
      prm[j] = p.P[j]; prm[5 + j] = p.M[j]; prm[10 + j] = p.Q[j]; prm[15 + j] = p.K[j];
    }
    prm[20] = p.AZ; prm[21] = p.dtczw; prm[22] = p.dtcz;
    prm[23] = p.cInt; prm[24] = p.cHv; prm[25] = p.cDir;
    for (int i = 0; i < 36; ++i) A0s[i] = 0.f;
    A0s[0] = p.AZ;
    for (int j = 0; j < 5; ++j) {
      A0s[0 * 6 + 1 + j]       = p.K[j];
      A0s[(1 + j) * 6 + 0]     = p.P[j];
      A0s[(1 + j) * 6 + 1 + j] = p.M[j];
    }
  }
  __syncthreads();
  int i6 = ln / 6, j6 = ln % 6;
  bool act = ln < 36;
#define MM(DST, L, R) { if (act) { float s = 0.f; \
  for (int m = 0; m < 6; ++m) s = fmaf((L)[i6 * 6 + m], (R)[m * 6 + j6], s); \
  (DST)[ln] = s; } __syncthreads(); }
  MM(Mb, A0s, A0s);  // A^2
  MM(Ma, Mb, Mb);    // A^4
  MM(Mb, Ma, Ma);    // A^8
  MM(Ma, Mb, Mb);    // A^16
  if (act) ws[A16_OFF + ln] = Ma[ln];
  // V[kk] = row0(A^(kk+1)), kk = 0..15
  if (ln < 6) vrow[0][ln] = A0s[ln];
  __syncthreads();
  int cur = 0;
  for (int kk = 0; kk < CL2; ++kk) {
    if (ln < 6) {
      ws[V_OFF + kk * 8 + ln] = vrow[cur][ln];
      float s = 0.f;
      for (int m = 0; m < 6; ++m) s = fmaf(vrow[cur][m], A0s[m * 6 + ln], s);
      vrow[1 - cur][ln] = s;
    }
    __syncthreads();
    cur ^= 1;
  }
}

// ============ KB2: fused MLP + chunk scan, LDS-staged coalesced reads ============
// Block = 256 consecutive batches x 1 chunk. blockIdx: c = bi>>3, b-group = bi&7.
__global__ __launch_bounds__(256) void kb2_scan(const float* __restrict__ X,
    const float* __restrict__ W1, const float* __restrict__ B1,
    const float* __restrict__ W2, const float* __restrict__ B2,
    float* __restrict__ out, float* __restrict__ ws) {
  __shared__ float lds[256 * 29];   // 4 steps x 7 floats per row, stride 29 (conflict-free)
  int c  = blockIdx.x >> 3;                    // 0..87
  int b0 = (blockIdx.x & 7) << 8;
  int b  = b0 + threadIdx.x;
  const float* prm = ws + PRM_OFF;             // uniform -> SGPRs
  float Pa[5], Mm[5], Qa[5], Ka[5];
  #pragma unroll
  for (int j = 0; j < 5; ++j) {
    Pa[j] = prm[j]; Mm[j] = prm[5 + j]; Qa[j] = prm[10 + j]; Ka[j] = prm[15 + j];
  }
  float AZ = prm[20], dtczw = prm[21], dtcz = prm[22];
  float cInt = prm[23], cHv = prm[24], cDir = prm[25];
  float b2 = B2[0];
  bool isc0 = (c == 0);
  int t0 = isc0 ? 0 : CL0 + (c - 1) * CL2;
  int NR = isc0 ? (CL0 / 4) : (CL2 / 4);       // staging rounds of 4 steps
  const float* xb = X + (size_t)b * T7;
  float Tz = 0.f, T0 = 0.f, T1 = 0.f, T2 = 0.f, T3 = 0.f, T4 = 0.f;
  float* op = out + (size_t)b * TLEN + t0;
  int j29 = threadIdx.x * 29;

  for (int r = 0; r < NR; ++r) {
    int t0r = t0 + r * 4;
    // ---- stage 256 rows x 4 steps (7 aligned float4 per row) ----
    const float* base = X + ((size_t)b0 * TLEN + t0r) * 7;
    #pragma unroll
    for (int i = 0; i < 7; ++i) {
      int F = i * 256 + threadIdx.x;           // 0..1791
      int row = F / 7, q = F - row * 7;
      float4 v = *(const float4*)(base + (size_t)row * T7 + q * 4);
      int la = row * 29 + q * 4;
      lds[la] = v.x; lds[la + 1] = v.y; lds[la + 2] = v.z; lds[la + 3] = v.w;
    }
    __syncthreads();
    if (isc0 && r == 0) {
      float tz0 = lds[j29], ta0 = lds[j29 + 1];
      Tz = tz0;
      T0 = T1 = T2 = T3 = T4 = fmaf(0.7f, tz0, 0.3f * ta0);
    }
    // boundary gt for step k%4==3 (chunk 0 only): next round's step-0 dword 0
    float gtb = 0.f;
    if (isc0 && (r * 4 + 3) < 47) gtb = xb[(size_t)(t0r + 4) * 7];
    float o0 = 0.f, o1 = 0.f, o2 = 0.f, o3 = 0.f;
    #pragma unroll
    for (int s = 0; s < 4; ++s) {
      const float* x = &lds[j29 + s * 7];
      float ta = x[1], so = x[2], x3 = x[3], x4v = x[4], x5 = x[5], hv = x[6];
      float acc = b2;
      #pragma unroll
      for (int h = 0; h < 32; ++h) {
        float z = fmaf(W1[2 * h], x3, fmaf(W1[2 * h + 1], x4v, B1[h]));
        acc = fmaf(W2[h], fmaxf(z, 0.f), acc);
      }
      float sch = __frcp_rn(1.f + __expf(-acc)) + x5;
      float q = fmaf(cInt, sch, fmaf(cHv, hv, cDir * so));
      float u = fmaf(dtczw, ta, dtcz * q);
      float d = fmaf(Ka[0], T0, u);
      d = fmaf(Ka[1], T1, d); d = fmaf(Ka[2], T2, d);
      d = fmaf(Ka[3], T3, d); d = fmaf(Ka[4], T4, d);
      float tzn = fmaf(AZ, Tz, d);
      T0 = fmaf(Mm[0], T0, fmaf(Pa[0], Tz, fmaf(Pa[0], ta, Qa[0] * so)));
      T1 = fmaf(Mm[1], T1, fmaf(Pa[1], Tz, fmaf(Pa[1], ta, Qa[1] * so)));
      T2 = fmaf(Mm[2], T2, fmaf(Pa[2], Tz, fmaf(Pa[2], ta, Qa[2] * so)));
      T3 = fmaf(Mm[3], T3, fmaf(Pa[3], Tz, fmaf(Pa[3], ta, Qa[3] * so)));
      T4 = fmaf(Mm[4], T4, fmaf(Pa[4], Tz, fmaf(Pa[4], ta, Qa[4] * so)));
      if (s == 0) o0 = tzn; else if (s == 1) o1 = tzn;
      else if (s == 2) o2 = tzn; else o3 = tzn;
      int k = r * 4 + s;
      float gt = (s < 3) ? lds[j29 + (s + 1) * 7] : gtb;
      Tz = (isc0 && k < 47) ? gt : tzn;
    }
    *(float4*)(op + r * 4) = make_float4(o0, o1, o2, o3);
    __syncthreads();   // protect LDS before next staging round
  }
  float* e = ws + E_OFF + ((size_t)c * BATCH + b) * 8;
  *(float4*)e       = make_float4(Tz, T0, T1, T2);
  *(float4*)(e + 4) = make_float4(T3, T4, 0.f, 0.f);
}

// ============ K2b: sequential chunk-state combine X_{c+1} = A16 X_c + e_c ============
__global__ __launch_bounds__(256) void k2b_combine(float* __restrict__ ws) {
  int b = blockIdx.x * 256 + threadIdx.x;  // < BATCH
  float A16r[36];
  #pragma unroll
  for (int i = 0; i < 36; ++i) A16r[i] = ws[A16_OFF + i];  // uniform -> SGPRs
  const float* e = ws + E_OFF;
  float4 h0 = *(const float4*)(e + (size_t)b * 8);
  float2 h1 = *(const float2*)(e + (size_t)b * 8 + 4);
  float Xs[6] = {h0.x, h0.y, h0.z, h0.w, h1.x, h1.y};   // X_1 = exact end of chunk 0
  float* xc = ws + XC_OFF + (size_t)b * NCH * 8;
  // prefetch e[1][b]
  float4 q0 = *(const float4*)(e + ((size_t)1 * BATCH + b) * 8);
  float2 q1 = *(const float2*)(e + ((size_t)1 * BATCH + b) * 8 + 4);
  for (int cI = 1; cI < NCH; ++cI) {
    *(float4*)(xc + cI * 8)     = make_float4(Xs[0], Xs[1], Xs[2], Xs[3]);
    *(float2*)(xc + cI * 8 + 4) = make_float2(Xs[4], Xs[5]);
    if (cI < NCH - 1) {
      const float* en = e + ((size_t)(cI + 1) * BATCH + b) * 8;
      float4 n0 = *(const float4*)en;
      float2 n1 = *(const float2*)(en + 4);
      float ecur[6] = {q0.x, q0.y, q0.z, q0.w, q1.x, q1.y};
      float Y[6];
      #pragma unroll
      for (int i = 0; i < 6; ++i) {
        float s = ecur[i];
        #pragma unroll
        for (int m = 0; m < 6; ++m) s = fmaf(A16r[i * 6 + m], Xs[m], s);
        Y[i] = s;
      }
      #pragma unroll
      for (int j = 0; j < 6; ++j) Xs[j] = Y[j];
      q0 = n0; q1 = n1;
    }
  }
}

// ============ K2c: superposition correction for t >= 48 ============
__global__ __launch_bounds__(256) void k2c_correct(float* __restrict__ out,
                                                   const float* __restrict__ ws) {
  int tid = blockIdx.x * 256 + threadIdx.x;  // < BATCH*TREST (exact grid)
  int b  = tid / TREST;
  int tt = tid - b * TREST;          // 0..1391
  int c  = (tt >> 4) + 1;            // 1..87
  int kk = tt & 15;
  const float* xc = ws + XC_OFF + ((size_t)b * NCH + c) * 8;
  float4 x0 = *(const float4*)xc;
  float2 x1 = *(const float2*)(xc + 4);
  const float* v = ws + V_OFF + kk * 8;
  float4 v0 = *(const float4*)v;
  float2 v1 = *(const float2*)(v + 4);
  size_t o = (size_t)b * TLEN + CL0 + tt;
  float s = out[o];
  s = fmaf(v0.x, x0.x, s); s = fmaf(v0.y, x0.y, s); s = fmaf(v0.z, x0.z, s);
  s = fmaf(v0.w, x0.w, s); s = fmaf(v1.x, x1.x, s); s = fmaf(v1.y, x1.y, s);
  out[o] = s;
}

// ============ Fallback: plain per-batch scan (if ws too small) ============
__global__ void k_fallback(const float* __restrict__ X,
    const float* __restrict__ rcR, const float* __restrict__ rcC,
    const float* __restrict__ winR, const float* __restrict__ hvg,
    const float* __restrict__ W1, const float* __restrict__ B1,
    const float* __restrict__ W2, const float* __restrict__ B2,
    const float* __restrict__ ing, const float* __restrict__ dg,
    const float* __restrict__ aw, const float* __restrict__ ar,
    const float* __restrict__ zc, float* __restrict__ out) {
  int b = blockIdx.x * 64 + threadIdx.x;
  if (b >= BATCH) return;
  Prm p = make_prm(rcR, rcC, winR, hvg, ing, dg, aw, ar, zc);
  const float* xb = X + (size_t)b * T7;
  float Tz = xb[0];
  float tm = fmaf(0.7f, xb[0], 0.3f * xb[1]);
  float Tm[5] = {tm, tm, tm, tm, tm};
  for (int t = 0; t < TLEN; ++t) {
    const float* x = xb + t * 7;
    float ta = x[1], so = x[2], x3 = x[3], x4 = x[4], x5 = x[5], hv = x[6];
    float acc = B2[0];
    #pragma unroll
    for (int h = 0; h < 32; ++h) {
      float z = fmaf(W1[2 * h], x3, fmaf(W1[2 * h + 1], x4, B1[h]));
      acc = fmaf(W2[h], fmaxf(z, 0.f), acc);
    }
    float sch = __frcp_rn(1.f + __expf(-acc)) + x5;
    float q = fmaf(p.cInt, sch, fmaf(p.cHv, hv, p.cDir * so));
    float u = fmaf(p.dtczw, ta, p.dtcz * q);
    float d = u;
    #pragma unroll
    for (int j = 0; j < 5; ++j) d = fmaf(p.K[j], Tm[j], d);
    float tzn = fmaf(p.AZ, Tz, d);
    #pragma unroll
    for (int j = 0; j < 5; ++j)
      Tm[j] = fmaf(p.M[j], Tm[j], fmaf(p.P[j], Tz, fmaf(p.P[j], ta, p.Q[j] * so)));
    out[(size_t)b * TLEN + t] = tzn;
    Tz = (t < 47) ? x[7] : tzn;
  }
}

extern "C" void kernel_launch(void* const* d_in, const int* in_sizes, int n_in,
                              void* d_out, int out_size, void* d_ws, size_t ws_size,
                              hipStream_t stream) {
  const float* X    = (const float*)d_in[0];
  const float* rcR  = (const float*)d_in[1];
  const float* rcC  = (const float*)d_in[2];
  const float* winR = (const float*)d_in[3];
  const float* hvg  = (const float*)d_in[4];
  const float* W1   = (const float*)d_in[5];
  const float* B1   = (const float*)d_in[6];
  const float* W2   = (const float*)d_in[7];
  const float* B2   = (const float*)d_in[8];
  const float* ing  = (const float*)d_in[9];
  const float* dg   = (const float*)d_in[10];
  const float* aw   = (const float*)d_in[11];
  const float* ar   = (const float*)d_in[12];
  const float* zc   = (const float*)d_in[13];
  float* out = (float*)d_out;
  float* ws  = (float*)d_ws;

  if (ws_size >= (size_t)WS_FLOATS * sizeof(float)) {
    k0_params<<<1, 64, 0, stream>>>(rcR, rcC, winR, hvg, ing, dg, aw, ar, zc, ws);
    kb2_scan<<<NCH * 8, 256, 0, stream>>>(X, W1, B1, W2, B2, out, ws);
    k2b_combine<<<BATCH / 256, 256, 0, stream>>>(ws);
    k2c_correct<<<(BATCH * TREST) / 256, 256, 0, stream>>>(out, ws);
  } else {
    k_fallback<<<BATCH / 64, 64, 0, stream>>>(X, rcR, rcC, winR, hvg, W1, B1, W2, B2,
                                              ing, dg, aw, ar, zc, out);
  }
}

// Round 4
// 246.079 us; speedup vs baseline: 1.0169x; 1.0169x over previous
//
#include <hip/hip_runtime.h>
#include <math.h>

#define BATCH 2048
#define TLEN  1440
#define T7    (TLEN * 7)      // 10080 dwords per batch row
#define CL0   48              // chunk 0 length (covers ENC_LEN=48 gt region)
#define CL2   16              // length of chunks 1..87
#define NCH   88              // total chunks per batch (1 + 87)
#define TREST (TLEN - CL0)    // 1392

// ---- workspace layout (float offsets) ----
#define PACK_OFF 0                               // float4[TLEN][BATCH] = 47.2 MB
#define E_OFF    (TLEN * BATCH * 4)              // [NCH][BATCH][8] chunk end-states
#define XC_OFF   (E_OFF + NCH * BATCH * 8)       // [BATCH][NCH][8] combined entry states
#define A16_OFF  (XC_OFF + BATCH * NCH * 8)      // 36 floats (pad 64)
#define V_OFF    (A16_OFF + 64)                  // [16][8]: V[kk][j] = row0(A^(kk+1))[j]
#define PRM_OFF  (V_OFF + 128)
#define WS_FLOATS (PRM_OFF + 32)

__device__ __forceinline__ float sp_precise(float x) { return log1pf(expf(x)); }

struct Prm {
  float P[5], M[5], Q[5], K[5];
  float AZ, dtczw, dtcz, cInt, cHv, cDir;
};
__device__ __forceinline__ Prm make_prm(const float* rcR, const float* rcC,
                                        const float* winR, const float* hvg,
                                        const float* ing, const float* dg,
                                        const float* aw, const float* ar,
                                        const float* zc) {
  Prm p;
  float r[5], cc[5], rsum = 0.f;
  #pragma unroll
  for (int j = 0; j < 5; ++j) {
    r[j] = sp_precise(rcR[j]) * 0.1f;
    cc[j] = sp_precise(rcC[j]) * 1e-5f;
    rsum += r[j];
  }
  float w  = (sp_precise(winR[0]) + sp_precise(winR[1])) * 0.5f;
  float cz = sp_precise(zc[0]) * 1e-5f;
  float aW = sp_precise(aw[0]) * 0.5f, aR = sp_precise(ar[0]) * 0.5f;
  float dtcz = 900.f * cz;
  #pragma unroll
  for (int j = 0; j < 5; ++j) {
    p.P[j] = 900.f * r[j] * cc[j];
    p.M[j] = 1.f - 2.f * p.P[j];
    p.Q[j] = 900.f * cc[j] * ((j < 4) ? aW : aR);
    p.K[j] = dtcz * r[j];
  }
  p.AZ = 1.f - dtcz * (w + rsum);
  p.dtczw = dtcz * w;
  p.dtcz = dtcz;
  p.cInt = sp_precise(ing[0]) * 0.1f;
  p.cHv  = sp_precise(hvg[0]) * 0.1f;
  p.cDir = sp_precise(dg[0])  * 0.5f;
  return p;
}

// ============ K0: derived params, A^16, V rows ============
__global__ void k0_params(const float* __restrict__ rcR, const float* __restrict__ rcC,
                          const float* __restrict__ winR, const float* __restrict__ hvg,
                          const float* __restrict__ ing, const float* __restrict__ dg,
                          const float* __restrict__ aw, const float* __restrict__ ar,
                          const float* __restrict__ zc, float* __restrict__ ws) {
  __shared__ float A0s[36], Ma[36], Mb[36], vrow[2][8];
  int ln = threadIdx.x;
  if (ln == 0) {
    Prm p = make_prm(rcR, rcC, winR, hvg, ing, dg, aw, ar, zc);
    float* prm = ws + PRM_OFF;
    for (int j = 0; j < 5; ++j) {
      prm[j] = p.P[j]; prm[5 + j] = p.M[j]; prm[10 + j] = p.Q[j]; prm[15 + j] = p.K[j];
    }
    prm[20] = p.AZ; prm[21] = p.dtczw; prm[22] = p.dtcz;
    prm[23] = p.cInt; prm[24] = p.cHv; prm[25] = p.cDir;
    for (int i = 0; i < 36; ++i) A0s[i] = 0.f;
    A0s[0] = p.AZ;
    for (int j = 0; j < 5; ++j) {
      A0s[0 * 6 + 1 + j]       = p.K[j];
      A0s[(1 + j) * 6 + 0]     = p.P[j];
      A0s[(1 + j) * 6 + 1 + j] = p.M[j];
    }
  }
  __syncthreads();
  int i6 = ln / 6, j6 = ln % 6;
  bool act = ln < 36;
#define MM(DST, L, R) { if (act) { float s = 0.f; \
  for (int m = 0; m < 6; ++m) s = fmaf((L)[i6 * 6 + m], (R)[m * 6 + j6], s); \
  (DST)[ln] = s; } __syncthreads(); }
  MM(Mb, A0s, A0s);  // A^2
  MM(Ma, Mb, Mb);    // A^4
  MM(Mb, Ma, Ma);    // A^8
  MM(Ma, Mb, Mb);    // A^16
  if (act) ws[A16_OFF + ln] = Ma[ln];
  // V[kk] = row0(A^(kk+1)), kk = 0..15
  if (ln < 6) vrow[0][ln] = A0s[ln];
  __syncthreads();
  int cur = 0;
  for (int kk = 0; kk < CL2; ++kk) {
    if (ln < 6) {
      ws[V_OFF + kk * 8 + ln] = vrow[cur][ln];
      float s = 0.f;
      for (int m = 0; m < 6; ++m) s = fmaf(vrow[cur][m], A0s[m * 6 + ln], s);
      vrow[1 - cur][ln] = s;
    }
    __syncthreads();
    cur ^= 1;
  }
}

// ============ K1: streaming MLP + forcing pack, transposed [t][BATCH] ============
// Block = 256 consecutive batches x 4 steps. Coalesced LDS-staged reads,
// coalesced transposed float4 writes. Grid = 360 t-groups x 8 b-groups = 2880.
__global__ __launch_bounds__(256) void k1_pack(const float* __restrict__ X,
    const float* __restrict__ W1, const float* __restrict__ B1,
    const float* __restrict__ W2, const float* __restrict__ B2,
    float* __restrict__ ws) {
  __shared__ float lds[256 * 29];   // 4 steps x 7 floats per row, stride 29
  int tg  = blockIdx.x >> 3;                   // 0..359
  int b0  = (blockIdx.x & 7) << 8;
  int t0r = tg * 4;
  int tid = threadIdx.x;
  int b   = b0 + tid;
  const float* prm = ws + PRM_OFF;             // uniform -> SGPRs
  float dtczw = prm[21], dtcz = prm[22];
  float cInt = prm[23], cHv = prm[24], cDir = prm[25];
  float b2 = B2[0];
  // ---- stage 256 rows x 4 steps (7 aligned float4 per row) ----
  const float* base = X + ((size_t)b0 * TLEN + t0r) * 7;
  #pragma unroll
  for (int i = 0; i < 7; ++i) {
    int F = i * 256 + tid;                     // 0..1791
    int row = F / 7, q = F - row * 7;
    float4 v = *(const float4*)(base + (size_t)row * T7 + q * 4);
    int la = row * 29 + q * 4;
    lds[la] = v.x; lds[la + 1] = v.y; lds[la + 2] = v.z; lds[la + 3] = v.w;
  }
  // boundary gt for s==3 (needed only while t+1 <= 47)
  float gtb = 0.f;
  if (t0r < 44) gtb = X[(size_t)b * T7 + (size_t)(t0r + 4) * 7];
  __syncthreads();
  int j29 = tid * 29;
  float4* pk = (float4*)(ws + PACK_OFF);
  #pragma unroll
  for (int s = 0; s < 4; ++s) {
    const float* x = &lds[j29 + s * 7];
    float ta = x[1], so = x[2], x3 = x[3], x4v = x[4], x5 = x[5], hv = x[6];
    float acc = b2;
    #pragma unroll
    for (int h = 0; h < 32; ++h) {
      float z = fmaf(W1[2 * h], x3, fmaf(W1[2 * h + 1], x4v, B1[h]));
      acc = fmaf(W2[h], fmaxf(z, 0.f), acc);
    }
    float sch = __frcp_rn(1.f + __expf(-acc)) + x5;
    float q = fmaf(cInt, sch, fmaf(cHv, hv, cDir * so));
    float u = fmaf(dtczw, ta, dtcz * q);
    int t = t0r + s;
    float gt = (t < 47) ? ((s < 3) ? lds[j29 + (s + 1) * 7] : gtb) : 0.f;
    pk[(size_t)t * BATCH + b] = make_float4(ta, so, u, gt);  // coalesced across lanes
  }
}

// ============ K2: chunk scan over packed forcings (coalesced reads) ============
__global__ __launch_bounds__(256) void k2_scan(const float* __restrict__ X,
                                               float* __restrict__ out,
                                               float* __restrict__ ws) {
  int c = blockIdx.x >> 3;                     // 0..87
  int b = ((blockIdx.x & 7) << 8) + threadIdx.x;
  const float* prm = ws + PRM_OFF;
  float Pa[5], Mm[5], Qa[5], Ka[5];
  #pragma unroll
  for (int j = 0; j < 5; ++j) {
    Pa[j] = prm[j]; Mm[j] = prm[5 + j]; Qa[j] = prm[10 + j]; Ka[j] = prm[15 + j];
  }
  float AZ = prm[20];
  bool isc0 = (c == 0);
  int t0 = isc0 ? 0 : CL0 + (c - 1) * CL2;
  int steps = isc0 ? CL0 : CL2;
  float Tz = 0.f, T0 = 0.f, T1 = 0.f, T2 = 0.f, T3 = 0.f, T4 = 0.f;
  if (isc0) {
    float tz0 = X[(size_t)b * T7];
    float ta0 = X[(size_t)b * T7 + 1];
    Tz = tz0;
    T0 = T1 = T2 = T3 = T4 = fmaf(0.7f, tz0, 0.3f * ta0);
  }
  const float4* pk = ((const float4*)(ws + PACK_OFF)) + (size_t)t0 * BATCH + b;
  float* op = out + (size_t)b * TLEN + t0;
  float o0 = 0.f, o1 = 0.f, o2 = 0.f;
  #pragma unroll 4
  for (int k = 0; k < steps; ++k) {
    float4 f = pk[(size_t)k * BATCH];          // coalesced 16B/lane
    float d = fmaf(Ka[0], T0, f.z);
    d = fmaf(Ka[1], T1, d); d = fmaf(Ka[2], T2, d);
    d = fmaf(Ka[3], T3, d); d = fmaf(Ka[4], T4, d);
    float tzn = fmaf(AZ, Tz, d);
    T0 = fmaf(Mm[0], T0, fmaf(Pa[0], Tz, fmaf(Pa[0], f.x, Qa[0] * f.y)));
    T1 = fmaf(Mm[1], T1, fmaf(Pa[1], Tz, fmaf(Pa[1], f.x, Qa[1] * f.y)));
    T2 = fmaf(Mm[2], T2, fmaf(Pa[2], Tz, fmaf(Pa[2], f.x, Qa[2] * f.y)));
    T3 = fmaf(Mm[3], T3, fmaf(Pa[3], Tz, fmaf(Pa[3], f.x, Qa[3] * f.y)));
    T4 = fmaf(Mm[4], T4, fmaf(Pa[4], Tz, fmaf(Pa[4], f.x, Qa[4] * f.y)));
    int ph = k & 3;
    if (ph == 0) o0 = tzn; else if (ph == 1) o1 = tzn;
    else if (ph == 2) o2 = tzn;
    else *(float4*)(op + (k - 3)) = make_float4(o0, o1, o2, tzn);
    Tz = (isc0 && k < 47) ? f.w : tzn;
  }
  float* e = ws + E_OFF + ((size_t)c * BATCH + b) * 8;
  *(float4*)e       = make_float4(Tz, T0, T1, T2);
  *(float4*)(e + 4) = make_float4(T3, T4, 0.f, 0.f);
}

// ============ K2b: sequential chunk-state combine X_{c+1} = A16 X_c + e_c ============
__global__ __launch_bounds__(256) void k2b_combine(float* __restrict__ ws) {
  int b = blockIdx.x * 256 + threadIdx.x;  // < BATCH
  float A16r[36];
  #pragma unroll
  for (int i = 0; i < 36; ++i) A16r[i] = ws[A16_OFF + i];  // uniform -> SGPRs
  const float* e = ws + E_OFF;
  float4 h0 = *(const float4*)(e + (size_t)b * 8);
  float2 h1 = *(const float2*)(e + (size_t)b * 8 + 4);
  float Xs[6] = {h0.x, h0.y, h0.z, h0.w, h1.x, h1.y};   // X_1 = exact end of chunk 0
  float* xc = ws + XC_OFF + (size_t)b * NCH * 8;
  float4 q0 = *(const float4*)(e + ((size_t)1 * BATCH + b) * 8);
  float2 q1 = *(const float2*)(e + ((size_t)1 * BATCH + b) * 8 + 4);
  for (int cI = 1; cI < NCH; ++cI) {
    *(float4*)(xc + cI * 8)     = make_float4(Xs[0], Xs[1], Xs[2], Xs[3]);
    *(float2*)(xc + cI * 8 + 4) = make_float2(Xs[4], Xs[5]);
    if (cI < NCH - 1) {
      const float* en = e + ((size_t)(cI + 1) * BATCH + b) * 8;
      float4 n0 = *(const float4*)en;
      float2 n1 = *(const float2*)(en + 4);
      float ecur[6] = {q0.x, q0.y, q0.z, q0.w, q1.x, q1.y};
      float Y[6];
      #pragma unroll
      for (int i = 0; i < 6; ++i) {
        float s = ecur[i];
        #pragma unroll
        for (int m = 0; m < 6; ++m) s = fmaf(A16r[i * 6 + m], Xs[m], s);
        Y[i] = s;
      }
      #pragma unroll
      for (int j = 0; j < 6; ++j) Xs[j] = Y[j];
      q0 = n0; q1 = n1;
    }
  }
}

// ============ K2c: superposition correction for t >= 48 ============
__global__ __launch_bounds__(256) void k2c_correct(float* __restrict__ out,
                                                   const float* __restrict__ ws) {
  int tid = blockIdx.x * 256 + threadIdx.x;  // < BATCH*TREST (exact grid)
  int b  = tid / TREST;
  int tt = tid - b * TREST;          // 0..1391
  int c  = (tt >> 4) + 1;            // 1..87
  int kk = tt & 15;
  const float* xc = ws + XC_OFF + ((size_t)b * NCH + c) * 8;
  float4 x0 = *(const float4*)xc;
  float2 x1 = *(const float2*)(xc + 4);
  const float* v = ws + V_OFF + kk * 8;
  float4 v0 = *(const float4*)v;
  float2 v1 = *(const float2*)(v + 4);
  size_t o = (size_t)b * TLEN + CL0 + tt;
  float s = out[o];
  s = fmaf(v0.x, x0.x, s); s = fmaf(v0.y, x0.y, s); s = fmaf(v0.z, x0.z, s);
  s = fmaf(v0.w, x0.w, s); s = fmaf(v1.x, x1.x, s); s = fmaf(v1.y, x1.y, s);
  out[o] = s;
}

// ============ Fallback: plain per-batch scan (if ws too small) ============
__global__ void k_fallback(const float* __restrict__ X,
    const float* __restrict__ rcR, const float* __restrict__ rcC,
    const float* __restrict__ winR, const float* __restrict__ hvg,
    const float* __restrict__ W1, const float* __restrict__ B1,
    const float* __restrict__ W2, const float* __restrict__ B2,
    const float* __restrict__ ing, const float* __restrict__ dg,
    const float* __restrict__ aw, const float* __restrict__ ar,
    const float* __restrict__ zc, float* __restrict__ out) {
  int b = blockIdx.x * 64 + threadIdx.x;
  if (b >= BATCH) return;
  Prm p = make_prm(rcR, rcC, winR, hvg, ing, dg, aw, ar, zc);
  const float* xb = X + (size_t)b * T7;
  float Tz = xb[0];
  float tm = fmaf(0.7f, xb[0], 0.3f * xb[1]);
  float Tm[5] = {tm, tm, tm, tm, tm};
  for (int t = 0; t < TLEN; ++t) {
    const float* x = xb + t * 7;
    float ta = x[1], so = x[2], x3 = x[3], x4 = x[4], x5 = x[5], hv = x[6];
    float acc = B2[0];
    #pragma unroll
    for (int h = 0; h < 32; ++h) {
      float z = fmaf(W1[2 * h], x3, fmaf(W1[2 * h + 1], x4, B1[h]));
      acc = fmaf(W2[h], fmaxf(z, 0.f), acc);
    }
    float sch = __frcp_rn(1.f + __expf(-acc)) + x5;
    float q = fmaf(p.cInt, sch, fmaf(p.cHv, hv, p.cDir * so));
    float u = fmaf(p.dtczw, ta, p.dtcz * q);
    float d = u;
    #pragma unroll
    for (int j = 0; j < 5; ++j) d = fmaf(p.K[j], Tm[j], d);
    float tzn = fmaf(p.AZ, Tz, d);
    #pragma unroll
    for (int j = 0; j < 5; ++j)
      Tm[j] = fmaf(p.M[j], Tm[j], fmaf(p.P[j], Tz, fmaf(p.P[j], ta, p.Q[j] * so)));
    out[(size_t)b * TLEN + t] = tzn;
    Tz = (t < 47) ? x[7] : tzn;
  }
}

extern "C" void kernel_launch(void* const* d_in, const int* in_sizes, int n_in,
                              void* d_out, int out_size, void* d_ws, size_t ws_size,
                              hipStream_t stream) {
  const float* X    = (const float*)d_in[0];
  const float* rcR  = (const float*)d_in[1];
  const float* rcC  = (const float*)d_in[2];
  const float* winR = (const float*)d_in[3];
  const float* hvg  = (const float*)d_in[4];
  const float* W1   = (const float*)d_in[5];
  const float* B1   = (const float*)d_in[6];
  const float* W2   = (const float*)d_in[7];
  const float* B2   = (const float*)d_in[8];
  const float* ing  = (const float*)d_in[9];
  const float* dg   = (const float*)d_in[10];
  const float* aw   = (const float*)d_in[11];
  const float* ar   = (const float*)d_in[12];
  const float* zc   = (const float*)d_in[13];
  float* out = (float*)d_out;
  float* ws  = (float*)d_ws;

  if (ws_size >= (size_t)WS_FLOATS * sizeof(float)) {
    k0_params<<<1, 64, 0, stream>>>(rcR, rcC, winR, hvg, ing, dg, aw, ar, zc, ws);
    k1_pack<<<(TLEN / 4) * 8, 256, 0, stream>>>(X, W1, B1, W2, B2, ws);
    k2_scan<<<NCH * 8, 256, 0, stream>>>(X, out, ws);
    k2b_combine<<<BATCH / 256, 256, 0, stream>>>(ws);
    k2c_correct<<<(BATCH * TREST) / 256, 256, 0, stream>>>(out, ws);
  } else {
    k_fallback<<<BATCH / 64, 64, 0, stream>>>(X, rcR, rcC, winR, hvg, W1, B1, W2, B2,
                                              ing, dg, aw, ar, zc, out);
  }
}

// Round 5
// 214.932 us; speedup vs baseline: 1.1643x; 1.1449x over previous
//
#include <hip/hip_runtime.h>
#include <math.h>

#define BATCH 2048
#define TLEN  1440
#define T7    (TLEN * 7)      // 10080 dwords per batch row
#define CL0   48              // chunk 0 length (covers ENC_LEN=48 gt region)
#define CL2   16              // length of chunks 1..87
#define NCH   88              // total chunks per batch (1 + 87)
#define TREST (TLEN - CL0)    // 1392

// ---- workspace layout (float offsets) ----
#define PACK2_OFF 0                                  // float2[TLEN][BATCH] (ta,so)
#define PACKU_OFF (PACK2_OFF + 2 * TLEN * BATCH)     // float[TLEN][BATCH]  u
#define PACKG_OFF (PACKU_OFF + TLEN * BATCH)         // float[48][BATCH]    gt
#define INIT_OFF  (PACKG_OFF + 48 * BATCH)           // float2[BATCH] (Tz0, Tmid0)
#define E_OFF     (INIT_OFF + 2 * BATCH)             // [NCH][BATCH][8] chunk end-states
#define XC_OFF    (E_OFF + NCH * BATCH * 8)          // [NCH][BATCH][8] combined entry states
#define A16_OFF   (XC_OFF + NCH * BATCH * 8)         // 36 floats (pad 64)
#define V_OFF     (A16_OFF + 64)                     // [16][8]: V[kk][j] = row0(A^(kk+1))[j]
#define WP_OFF    (V_OFF + 128)                      // [32] float4 MLP weights
#define PRM_OFF   (WP_OFF + 128)
#define WS_FLOATS (PRM_OFF + 32)

__device__ __forceinline__ float sp_precise(float x) { return log1pf(expf(x)); }

struct Prm {
  float P[5], M[5], Q[5], K[5];
  float AZ, dtczw, dtcz, cInt, cHv, cDir;
};
__device__ __forceinline__ Prm make_prm(const float* rcR, const float* rcC,
                                        const float* winR, const float* hvg,
                                        const float* ing, const float* dg,
                                        const float* aw, const float* ar,
                                        const float* zc) {
  Prm p;
  float r[5], cc[5], rsum = 0.f;
  #pragma unroll
  for (int j = 0; j < 5; ++j) {
    r[j] = sp_precise(rcR[j]) * 0.1f;
    cc[j] = sp_precise(rcC[j]) * 1e-5f;
    rsum += r[j];
  }
  float w  = (sp_precise(winR[0]) + sp_precise(winR[1])) * 0.5f;
  float cz = sp_precise(zc[0]) * 1e-5f;
  float aW = sp_precise(aw[0]) * 0.5f, aR = sp_precise(ar[0]) * 0.5f;
  float dtcz = 900.f * cz;
  #pragma unroll
  for (int j = 0; j < 5; ++j) {
    p.P[j] = 900.f * r[j] * cc[j];
    p.M[j] = 1.f - 2.f * p.P[j];
    p.Q[j] = 900.f * cc[j] * ((j < 4) ? aW : aR);
    p.K[j] = dtcz * r[j];
  }
  p.AZ = 1.f - dtcz * (w + rsum);
  p.dtczw = dtcz * w;
  p.dtcz = dtcz;
  p.cInt = sp_precise(ing[0]) * 0.1f;
  p.cHv  = sp_precise(hvg[0]) * 0.1f;
  p.cDir = sp_precise(dg[0])  * 0.5f;
  return p;
}

// ============ K0: derived params, weight pack, A^16, V rows ============
__global__ void k0_params(const float* __restrict__ rcR, const float* __restrict__ rcC,
                          const float* __restrict__ winR, const float* __restrict__ hvg,
                          const float* __restrict__ W1, const float* __restrict__ B1,
                          const float* __restrict__ W2, const float* __restrict__ B2,
                          const float* __restrict__ ing, const float* __restrict__ dg,
                          const float* __restrict__ aw, const float* __restrict__ ar,
                          const float* __restrict__ zc, float* __restrict__ ws) {
  __shared__ float A0s[36], Ma[36], Mb[36], vrow[2][8];
  int ln = threadIdx.x;
  // weight pack: (W1[2h], W1[2h+1], B1[h], W2[h]) per h
  if (ln < 32) {
    ((float4*)(ws + WP_OFF))[ln] =
        make_float4(W1[2 * ln], W1[2 * ln + 1], B1[ln], W2[ln]);
  }
  if (ln == 0) {
    Prm p = make_prm(rcR, rcC, winR, hvg, ing, dg, aw, ar, zc);
    float* prm = ws + PRM_OFF;
    for (int j = 0; j < 5; ++j) {
      prm[j] = p.P[j]; prm[5 + j] = p.M[j]; prm[10 + j] = p.Q[j]; prm[15 + j] = p.K[j];
    }
    prm[20] = p.AZ; prm[21] = p.dtczw; prm[22] = p.dtcz;
    prm[23] = p.cInt; prm[24] = p.cHv; prm[25] = p.cDir;
    prm[26] = B2[0];
    for (int i = 0; i < 36; ++i) A0s[i] = 0.f;
    A0s[0] = p.AZ;
    for (int j = 0; j < 5; ++j) {
      A0s[0 * 6 + 1 + j]       = p.K[j];
      A0s[(1 + j) * 6 + 0]     = p.P[j];
      A0s[(1 + j) * 6 + 1 + j] = p.M[j];
    }
  }
  __syncthreads();
  int i6 = ln / 6, j6 = ln % 6;
  bool act = ln < 36;
#define MM(DST, L, R) { if (act) { float s = 0.f; \
  for (int m = 0; m < 6; ++m) s = fmaf((L)[i6 * 6 + m], (R)[m * 6 + j6], s); \
  (DST)[ln] = s; } __syncthreads(); }
  MM(Mb, A0s, A0s);  // A^2
  MM(Ma, Mb, Mb);    // A^4
  MM(Mb, Ma, Ma);    // A^8
  MM(Ma, Mb, Mb);    // A^16
  if (act) ws[A16_OFF + ln] = Ma[ln];
  // V[kk] = row0(A^(kk+1)), kk = 0..15
  if (ln < 6) vrow[0][ln] = A0s[ln];
  __syncthreads();
  int cur = 0;
  for (int kk = 0; kk < CL2; ++kk) {
    if (ln < 6) {
      ws[V_OFF + kk * 8 + ln] = vrow[cur][ln];
      float s = 0.f;
      for (int m = 0; m < 6; ++m) s = fmaf(vrow[cur][m], A0s[m * 6 + ln], s);
      vrow[1 - cur][ln] = s;
    }
    __syncthreads();
    cur ^= 1;
  }
}

// ============ K1: streaming MLP + forcing pack (weights via LDS) ============
// Block = 256 consecutive batches x 4 steps. Grid = 360 t-groups x 8 b-groups.
__global__ __launch_bounds__(256) void k1_pack(const float* __restrict__ X,
                                               float* __restrict__ ws) {
  __shared__ float lds[256 * 29];   // 4 steps x 7 floats per row, stride 29
  __shared__ float ldsW[128];       // 32 x float4 weight pack
  int tg  = blockIdx.x >> 3;                   // 0..359
  int b0  = (blockIdx.x & 7) << 8;
  int t0r = tg * 4;
  int tid = threadIdx.x;
  int b   = b0 + tid;
  const float* prm = ws + PRM_OFF;             // uniform -> SGPRs
  float dtczw = prm[21], dtcz = prm[22];
  float cInt = prm[23], cHv = prm[24], cDir = prm[25];
  float b2 = prm[26];
  if (tid < 32) *(float4*)&ldsW[tid * 4] = ((const float4*)(ws + WP_OFF))[tid];
  // ---- stage 256 rows x 4 steps (7 aligned float4 per row) ----
  const float* base = X + ((size_t)b0 * TLEN + t0r) * 7;
  #pragma unroll
  for (int i = 0; i < 7; ++i) {
    int F = i * 256 + tid;                     // 0..1791
    int row = F / 7, q = F - row * 7;
    float4 v = *(const float4*)(base + (size_t)row * T7 + q * 4);
    int la = row * 29 + q * 4;
    lds[la] = v.x; lds[la + 1] = v.y; lds[la + 2] = v.z; lds[la + 3] = v.w;
  }
  // boundary gt for s==3 (needed only while t+1 <= 47)
  float gtb = 0.f;
  if (t0r < 44) gtb = X[(size_t)b * T7 + (size_t)(t0r + 4) * 7];
  __syncthreads();
  int j29 = tid * 29;
  // gather per-step inputs from own row
  float ta[4], so[4], x3[4], x4[4], x5[4], hv[4];
  #pragma unroll
  for (int s = 0; s < 4; ++s) {
    const float* x = &lds[j29 + s * 7];
    ta[s] = x[1]; so[s] = x[2]; x3[s] = x[3]; x4[s] = x[4]; x5[s] = x[5]; hv[s] = x[6];
  }
  // MLP: h-outer, one ds_read_b128 broadcast per h, reused across 4 steps
  float acc[4] = {b2, b2, b2, b2};
  #pragma unroll
  for (int h = 0; h < 32; ++h) {
    float4 wv = *(const float4*)&ldsW[h * 4];
    #pragma unroll
    for (int s = 0; s < 4; ++s) {
      float z = fmaf(wv.x, x3[s], fmaf(wv.y, x4[s], wv.z));
      acc[s] = fmaf(wv.w, fmaxf(z, 0.f), acc[s]);
    }
  }
  float2* pk2 = (float2*)(ws + PACK2_OFF);
  float*  pu  = ws + PACKU_OFF;
  float*  pg  = ws + PACKG_OFF;
  #pragma unroll
  for (int s = 0; s < 4; ++s) {
    float sch = __frcp_rn(1.f + __expf(-acc[s])) + x5[s];
    float q = fmaf(cInt, sch, fmaf(cHv, hv[s], cDir * so[s]));
    float u = fmaf(dtczw, ta[s], dtcz * q);
    int t = t0r + s;
    size_t o = (size_t)t * BATCH + b;
    pk2[o] = make_float2(ta[s], so[s]);        // coalesced 8B/lane
    pu[o]  = u;                                // coalesced 4B/lane
    if (t < 48) {
      float gt = (t < 47) ? ((s < 3) ? lds[j29 + (s + 1) * 7] : gtb) : 0.f;
      pg[o] = gt;
    }
  }
  if (tg == 0) {  // init states (Tz0, Tmid0), coalesced
    float tz0 = lds[j29], ta0 = lds[j29 + 1];
    ((float2*)(ws + INIT_OFF))[b] = make_float2(tz0, fmaf(0.7f, tz0, 0.3f * ta0));
  }
}

// ============ K2: chunk scan over packed forcings (coalesced reads) ============
__global__ __launch_bounds__(256) void k2_scan(float* __restrict__ out,
                                               float* __restrict__ ws) {
  int c = blockIdx.x >> 3;                     // 0..87
  int b = ((blockIdx.x & 7) << 8) + threadIdx.x;
  const float* prm = ws + PRM_OFF;
  float Pa[5], Mm[5], Qa[5], Ka[5];
  #pragma unroll
  for (int j = 0; j < 5; ++j) {
    Pa[j] = prm[j]; Mm[j] = prm[5 + j]; Qa[j] = prm[10 + j]; Ka[j] = prm[15 + j];
  }
  float AZ = prm[20];
  bool isc0 = (c == 0);
  int t0 = isc0 ? 0 : CL0 + (c - 1) * CL2;
  int steps = isc0 ? CL0 : CL2;
  float Tz = 0.f, T0 = 0.f, T1 = 0.f, T2 = 0.f, T3 = 0.f, T4 = 0.f;
  if (isc0) {
    float2 iv = ((const float2*)(ws + INIT_OFF))[b];
    Tz = iv.x;
    T0 = T1 = T2 = T3 = T4 = iv.y;
  }
  const float2* pk2 = ((const float2*)(ws + PACK2_OFF)) + (size_t)t0 * BATCH + b;
  const float*  pu  = ws + PACKU_OFF + (size_t)t0 * BATCH + b;
  const float*  pg  = ws + PACKG_OFF + b;      // only used when c==0 (t0==0)
  float* op = out + (size_t)b * TLEN + t0;
  float o0 = 0.f, o1 = 0.f, o2 = 0.f;
  #pragma unroll 4
  for (int k = 0; k < steps; ++k) {
    float2 f2 = pk2[(size_t)k * BATCH];        // ta, so
    float  uv = pu[(size_t)k * BATCH];
    float d = fmaf(Ka[0], T0, uv);
    d = fmaf(Ka[1], T1, d); d = fmaf(Ka[2], T2, d);
    d = fmaf(Ka[3], T3, d); d = fmaf(Ka[4], T4, d);
    float tzn = fmaf(AZ, Tz, d);
    T0 = fmaf(Mm[0], T0, fmaf(Pa[0], Tz, fmaf(Pa[0], f2.x, Qa[0] * f2.y)));
    T1 = fmaf(Mm[1], T1, fmaf(Pa[1], Tz, fmaf(Pa[1], f2.x, Qa[1] * f2.y)));
    T2 = fmaf(Mm[2], T2, fmaf(Pa[2], Tz, fmaf(Pa[2], f2.x, Qa[2] * f2.y)));
    T3 = fmaf(Mm[3], T3, fmaf(Pa[3], Tz, fmaf(Pa[3], f2.x, Qa[3] * f2.y)));
    T4 = fmaf(Mm[4], T4, fmaf(Pa[4], Tz, fmaf(Pa[4], f2.x, Qa[4] * f2.y)));
    int ph = k & 3;
    if (ph == 0) o0 = tzn; else if (ph == 1) o1 = tzn;
    else if (ph == 2) o2 = tzn;
    else *(float4*)(op + (k - 3)) = make_float4(o0, o1, o2, tzn);
    if (isc0 && k < 47) Tz = pg[(size_t)k * BATCH];
    else Tz = tzn;
  }
  float* e = ws + E_OFF + ((size_t)c * BATCH + b) * 8;
  *(float4*)e       = make_float4(Tz, T0, T1, T2);
  *(float4*)(e + 4) = make_float4(T3, T4, 0.f, 0.f);
}

// ============ K2b: sequential chunk-state combine, group-8 prefetch ============
__global__ __launch_bounds__(64) void k2b_combine(float* __restrict__ ws) {
  int b = blockIdx.x * 64 + threadIdx.x;  // < BATCH (32 blocks x 64)
  float A16r[36];
  #pragma unroll
  for (int i = 0; i < 36; ++i) A16r[i] = ws[A16_OFF + i];  // uniform -> SGPRs
  const float* e = ws + E_OFF;
  float4 h0 = *(const float4*)(e + (size_t)b * 8);
  float2 h1 = *(const float2*)(e + (size_t)b * 8 + 4);
  float Xs[6] = {h0.x, h0.y, h0.z, h0.w, h1.x, h1.y};   // X_1 = exact end of chunk 0
  for (int base = 1; base <= 87; base += 8) {
    float4 q0[8]; float2 q1[8];
    #pragma unroll
    for (int i = 0; i < 8; ++i) {              // 8 independent loads in flight
      int cI = base + i;
      if (cI <= 86) {
        const float* en = e + ((size_t)cI * BATCH + b) * 8;
        q0[i] = *(const float4*)en;
        q1[i] = *(const float2*)(en + 4);
      }
    }
    #pragma unroll
    for (int i = 0; i < 8; ++i) {
      int cI = base + i;
      if (cI > 87) break;
      float* xc = ws + XC_OFF + ((size_t)cI * BATCH + b) * 8;   // [c][b] coalesced
      *(float4*)xc       = make_float4(Xs[0], Xs[1], Xs[2], Xs[3]);
      *(float2*)(xc + 4) = make_float2(Xs[4], Xs[5]);
      if (cI <= 86) {
        float ecur[6] = {q0[i].x, q0[i].y, q0[i].z, q0[i].w, q1[i].x, q1[i].y};
        float Y[6];
        #pragma unroll
        for (int r = 0; r < 6; ++r) {
          float s = ecur[r];
          #pragma unroll
          for (int m = 0; m < 6; ++m) s = fmaf(A16r[r * 6 + m], Xs[m], s);
          Y[r] = s;
        }
        #pragma unroll
        for (int j = 0; j < 6; ++j) Xs[j] = Y[j];
      }
    }
  }
}

// ============ K2c: superposition correction for t >= 48 ============
__global__ __launch_bounds__(256) void k2c_correct(float* __restrict__ out,
                                                   const float* __restrict__ ws) {
  int tid = blockIdx.x * 256 + threadIdx.x;  // < BATCH*TREST (exact grid)
  int b  = tid / TREST;
  int tt = tid - b * TREST;          // 0..1391
  int c  = (tt >> 4) + 1;            // 1..87
  int kk = tt & 15;
  const float* xc = ws + XC_OFF + ((size_t)c * BATCH + b) * 8;
  float4 x0 = *(const float4*)xc;
  float2 x1 = *(const float2*)(xc + 4);
  const float* v = ws + V_OFF + kk * 8;
  float4 v0 = *(const float4*)v;
  float2 v1 = *(const float2*)(v + 4);
  size_t o = (size_t)b * TLEN + CL0 + tt;
  float s = out[o];
  s = fmaf(v0.x, x0.x, s); s = fmaf(v0.y, x0.y, s); s = fmaf(v0.z, x0.z, s);
  s = fmaf(v0.w, x0.w, s); s = fmaf(v1.x, x1.x, s); s = fmaf(v1.y, x1.y, s);
  out[o] = s;
}

// ============ Fallback: plain per-batch scan (if ws too small) ============
__global__ void k_fallback(const float* __restrict__ X,
    const float* __restrict__ rcR, const float* __restrict__ rcC,
    const float* __restrict__ winR, const float* __restrict__ hvg,
    const float* __restrict__ W1, const float* __restrict__ B1,
    const float* __restrict__ W2, const float* __restrict__ B2,
    const float* __restrict__ ing, const float* __restrict__ dg,
    const float* __restrict__ aw, const float* __restrict__ ar,
    const float* __restrict__ zc, float* __restrict__ out) {
  int b = blockIdx.x * 64 + threadIdx.x;
  if (b >= BATCH) return;
  Prm p = make_prm(rcR, rcC, winR, hvg, ing, dg, aw, ar, zc);
  const float* xb = X + (size_t)b * T7;
  float Tz = xb[0];
  float tm = fmaf(0.7f, xb[0], 0.3f * xb[1]);
  float Tm[5] = {tm, tm, tm, tm, tm};
  for (int t = 0; t < TLEN; ++t) {
    const float* x = xb + t * 7;
    float ta = x[1], so = x[2], x3 = x[3], x4 = x[4], x5 = x[5], hv = x[6];
    float acc = B2[0];
    #pragma unroll
    for (int h = 0; h < 32; ++h) {
      float z = fmaf(W1[2 * h], x3, fmaf(W1[2 * h + 1], x4, B1[h]));
      acc = fmaf(W2[h], fmaxf(z, 0.f), acc);
    }
    float sch = __frcp_rn(1.f + __expf(-acc)) + x5;
    float q = fmaf(p.cInt, sch, fmaf(p.cHv, hv, p.cDir * so));
    float u = fmaf(p.dtczw, ta, p.dtcz * q);
    float d = u;
    #pragma unroll
    for (int j = 0; j < 5; ++j) d = fmaf(p.K[j], Tm[j], d);
    float tzn = fmaf(p.AZ, Tz, d);
    #pragma unroll
    for (int j = 0; j < 5; ++j)
      Tm[j] = fmaf(p.M[j], Tm[j], fmaf(p.P[j], Tz, fmaf(p.P[j], ta, p.Q[j] * so)));
    out[(size_t)b * TLEN + t] = tzn;
    Tz = (t < 47) ? x[7] : tzn;
  }
}

extern "C" void kernel_launch(void* const* d_in, const int* in_sizes, int n_in,
                              void* d_out, int out_size, void* d_ws, size_t ws_size,
                              hipStream_t stream) {
  const float* X    = (const float*)d_in[0];
  const float* rcR  = (const float*)d_in[1];
  const float* rcC  = (const float*)d_in[2];
  const float* winR = (const float*)d_in[3];
  const float* hvg  = (const float*)d_in[4];
  const float* W1   = (const float*)d_in[5];
  const float* B1   = (const float*)d_in[6];
  const float* W2   = (const float*)d_in[7];
  const float* B2   = (const float*)d_in[8];
  const float* ing  = (const float*)d_in[9];
  const float* dg   = (const float*)d_in[10];
  const float* aw   = (const float*)d_in[11];
  const float* ar   = (const float*)d_in[12];
  const float* zc   = (const float*)d_in[13];
  float* out = (float*)d_out;
  float* ws  = (float*)d_ws;

  if (ws_size >= (size_t)WS_FLOATS * sizeof(float)) {
    k0_params<<<1, 64, 0, stream>>>(rcR, rcC, winR, hvg, W1, B1, W2, B2,
                                    ing, dg, aw, ar, zc, ws);
    k1_pack<<<(TLEN / 4) * 8, 256, 0, stream>>>(X, ws);
    k2_scan<<<NCH * 8, 256, 0, stream>>>(out, ws);
    k2b_combine<<<32, 64, 0, stream>>>(ws);
    k2c_correct<<<(BATCH * TREST) / 256, 256, 0, stream>>>(out, ws);
  } else {
    k_fallback<<<BATCH / 64, 64, 0, stream>>>(X, rcR, rcC, winR, hvg, W1, B1, W2, B2,
                                              ing, dg, aw, ar, zc, out);
  }
}